// Round 14
// baseline (669.200 us; speedup 1.0000x reference)
//
#include <hip/hip_runtime.h>
#include <hip/hip_bf16.h>

// Block-sparse FFN via compacted-weight MFMA, v14.
//   out = gelu(x @ (W1*M1)^T + b1) @ (W2*M2)^T + b2
// vs v13: (1) A-gathers index the __shared__ arrays DIRECTLY (&xs[off]) so the
// compiler can prove LDS addrspace -> ds_read_b128 (v11-13's char* generic
// pointers caused the flat/scratch regression: WRITE 110->216MB, VALUBusy drop);
// (2) pitches XP=778 / HP=1546: odd dword row stride -> b128 gathers hit every
// bank exactly 4x (minimum) -> structurally conflict-free (the old 1.8e7
// conflicts were row-stride aliasing at stride%32=4; column swizzles can't fix).
// idx streams hold u32 ELEMENT offsets (db*8). Identity group assignment.

typedef __attribute__((ext_vector_type(8))) short short8;
typedef __attribute__((ext_vector_type(16))) float f32x16;
typedef unsigned long long u64;
typedef unsigned short ushort_t;

#define DIM 768
#define FF 3072
#define NF32 96             // fc1 32-col groups
#define NG32 24             // fc2 32-col groups
#define NDB 96
#define NFB 384
#define MR 32
#define NT 768
#define XP 778              // xs pitch (bf16 elems) -> 389 dwords/row (odd)
#define HP 1546             // hs pitch (bf16 elems) -> 773 dwords/row (odd)
#define SACCP 773           // sacc pitch (f32), 32*773*4 = 98,944 B = sizeof(hs)

#define S1CAP (NF32 * 96 + 32)        // slots + prefetch margin
#define S2CAP (NG32 * 2 * 192 + 32)
#define W1S_TOT (S1CAP * 256)         // bf16 elems
#define W2S_TOT (S2CAP * 256)

#define MFMA32 __builtin_amdgcn_mfma_f32_32x32x16_bf16

__device__ __forceinline__ float gelu_fast(float v) {
    float t2 = v * fmaf(v * v, -0.10295667f, -2.30235629f);
    return v / (1.0f + exp2f(t2));
}
__device__ __forceinline__ ushort_t f2bs(float f) {
    union { __hip_bfloat16 h; ushort_t u; } cv;
    cv.h = __float2bfloat16(f);
    return cv.u;
}

// ---------------- prep 1: padded per-group counts ----------------
__global__ __launch_bounds__(64)
void prep_count(const int* __restrict__ mask1, const int* __restrict__ mask2,
                int* __restrict__ cnt1, int* __restrict__ cnt2)
{
    const int l = threadIdx.x;
    const int g = blockIdx.x;
    if (g < NF32) {
        const int* r0 = mask1 + (4 * g) * NDB;
        bool ua = (r0[l] | r0[NDB + l] | r0[2 * NDB + l] | r0[3 * NDB + l]) != 0;
        u64 ba = __ballot(ua);
        bool ub = (l < 32) &&
            ((r0[64 + l] | r0[NDB + 64 + l] | r0[2 * NDB + 64 + l] | r0[3 * NDB + 64 + l]) != 0);
        u64 bb = __ballot(ub);
        if (l == 0) cnt1[g] = ((__popcll(ba) + __popcll(bb)) + 15) & ~15;
    } else {
        const int G = g - NF32;
        const int* r0 = mask2 + (4 * G) * NFB;
        int c0 = 0, c1 = 0;
        #pragma unroll
        for (int p = 0; p < 6; ++p) {
            int fb = p * 64 + l;
            u64 b = __ballot((r0[fb] | r0[NFB + fb] | r0[2 * NFB + fb] | r0[3 * NFB + fb]) != 0);
            if (p < 3) c0 += __popcll(b); else c1 += __popcll(b);
        }
        if (l == 0) {
            cnt2[0 * NG32 + G] = (c0 + 15) & ~15;
            cnt2[1 * NG32 + G] = (c1 + 15) & ~15;
        }
    }
}

// ---------------- prep 2: trivial parallel prefix + tails ----------------
__global__ __launch_bounds__(128)
void prep_scan(const int* __restrict__ cnt1, const int* __restrict__ cnt2,
               int* __restrict__ off1p, int* __restrict__ off2p,
               int* __restrict__ base1, int* __restrict__ base2,
               unsigned* __restrict__ idx1s, unsigned* __restrict__ idx2s)
{
    __shared__ int s1[97], s2[49];
    const int tid = threadIdx.x;
    if (tid < 96) s1[tid + 1] = cnt1[tid];
    if (tid < 48) s2[tid + 1] = cnt2[tid];
    __syncthreads();
    if (tid == 0) { s1[0] = 0; for (int i = 0; i < 96; ++i) s1[i + 1] += s1[i]; }
    if (tid == 1) { s2[0] = 0; for (int i = 0; i < 48; ++i) s2[i + 1] += s2[i]; }
    __syncthreads();
    if (tid < 97) off1p[tid] = s1[tid];
    if (tid < 96) base1[tid] = s1[tid];
    if (tid < 49) off2p[tid] = s2[tid];
    if (tid < 48) base2[tid] = s2[tid];
    if (tid >= 64 && tid < 96) idx1s[s1[96] + (tid - 64)] = 0;    // safe overrun
    if (tid >= 96 && tid < 128) idx2s[s2[48] + (tid - 96)] = 0;
}

// ---------------- prep 3: gather weights + u32 element-offset indices ----------------
__global__ __launch_bounds__(256)
void prep_gather(const float* __restrict__ W1, const float* __restrict__ W2,
                 const int* __restrict__ mask1, const int* __restrict__ mask2,
                 const int* __restrict__ base1, const int* __restrict__ base2,
                 const int* __restrict__ cnt1, const int* __restrict__ cnt2,
                 __hip_bfloat16* __restrict__ w1s, __hip_bfloat16* __restrict__ w2s,
                 unsigned* __restrict__ idx1s, unsigned* __restrict__ idx2s)
{
    __shared__ ushort_t sidx[192];
    __shared__ int sc[1];
    const int tid = threadIdx.x;
    const int l = tid & 63;
    const int g = blockIdx.x;

    if (g < NF32) {                       // ---- fc1 group F ----
        const int F = g;
        const int* r0 = mask1 + (4 * F) * NDB;
        if (tid < 64) {
            bool ua = (r0[l] | r0[NDB + l] | r0[2 * NDB + l] | r0[3 * NDB + l]) != 0;
            u64 ba = __ballot(ua);
            bool ub = (l < 32) &&
                ((r0[64 + l] | r0[NDB + 64 + l] | r0[2 * NDB + 64 + l] | r0[3 * NDB + 64 + l]) != 0);
            u64 bb = __ballot(ub);
            int ca = __popcll(ba);
            if (ua) sidx[__popcll(ba & ((1ull << l) - 1ull))] = (ushort_t)l;
            if (ub) sidx[ca + __popcll(bb & ((1ull << l) - 1ull))] = (ushort_t)(64 + l);
            int cnt = ca + __popcll(bb);
            if (l == 0) {
                sc[0] = cnt;
                int cntp = (cnt + 15) & ~15;
                for (int i = cnt; i < cntp && i < 192; ++i) sidx[i] = 0;
            }
        }
        __syncthreads();
        const int cnt = sc[0];
        const int base = base1[F];
        const int cntp = cnt1[F];
        if (tid < cntp) idx1s[base + tid] = (unsigned)sidx[tid] * 8u;  // elem offset
        for (int e = tid; e < cntp * 256; e += 256) {
            int slot = e >> 8, c = (e >> 3) & 31, j = e & 7;
            int db = sidx[slot];
            float w = 0.f;
            if (slot < cnt && mask1[(4 * F + (c >> 3)) * NDB + db])
                w = W1[(long)(F * 32 + c) * DIM + db * 8 + j];
            w1s[(long)(base + slot) * 256 + c * 8 + j] = __float2bfloat16(w);
        }
    } else {                              // ---- fc2 (chunk, G) ----
        const int gi = g - NF32;
        const int c = gi / NG32;
        const int G = gi % NG32;
        const int* r0 = mask2 + (4 * G) * NFB;
        if (tid < 64) {
            u64 b[3]; int pc[3];
            #pragma unroll
            for (int p = 0; p < 3; ++p) {
                int fb = c * 192 + p * 64 + l;
                b[p] = __ballot((r0[fb] | r0[NFB + fb] | r0[2 * NFB + fb] | r0[3 * NFB + fb]) != 0);
                pc[p] = __popcll(b[p]);
            }
            int basea = 0;
            #pragma unroll
            for (int p = 0; p < 3; ++p) {
                if ((b[p] >> l) & 1ull)
                    sidx[basea + __popcll(b[p] & ((1ull << l) - 1ull))] = (ushort_t)(p * 64 + l);
                basea += pc[p];
            }
            if (l == 0) {
                int cnt = basea;
                sc[0] = cnt;
                int cntp = (cnt + 15) & ~15;
                for (int i = cnt; i < cntp && i < 192; ++i) sidx[i] = 0;
            }
        }
        __syncthreads();
        const int cnt = sc[0];
        const int base = base2[c * NG32 + G];
        const int cntp = cnt2[c * NG32 + G];
        if (tid < cntp) idx2s[base + tid] = (unsigned)sidx[tid] * 8u;  // elem offset
        for (int e = tid; e < cntp * 256; e += 256) {
            int slot = e >> 8, cc = (e >> 3) & 31, j = e & 7;
            int lfb = sidx[slot];
            int fb = c * 192 + lfb;
            float w = 0.f;
            if (slot < cnt && mask2[(4 * G + (cc >> 3)) * NFB + fb])
                w = W2[(long)(G * 32 + cc) * FF + fb * 8 + j];
            w2s[(long)(base + slot) * 256 + cc * 8 + j] = __float2bfloat16(w);
        }
    }
}

// ---------------- main fused kernel ----------------
// PREF: m* are u32 ELEMENT offsets; gathers index the shared array directly so
// the compiler can prove LDS addrspace (ds_read_b128).
#define PREF(BUF, IP, WP, ARR, ROWOFF)                                  \
    {                                                                   \
        uint4 qa = *(const uint4*)(IP);                                 \
        uint4 qb = *(const uint4*)((IP) + 4);                           \
        int m0 = lh ? (int)qa.y : (int)qa.x;                            \
        int m1 = lh ? (int)qa.w : (int)qa.z;                            \
        int m2 = lh ? (int)qb.y : (int)qb.x;                            \
        int m3 = lh ? (int)qb.w : (int)qb.z;                            \
        BUF##a0 = *(const short8*)&ARR[(ROWOFF) + m0];                  \
        BUF##a1 = *(const short8*)&ARR[(ROWOFF) + m1];                  \
        BUF##a2 = *(const short8*)&ARR[(ROWOFF) + m2];                  \
        BUF##a3 = *(const short8*)&ARR[(ROWOFF) + m3];                  \
        BUF##w0 = *(const short8*)(WP);                                 \
        BUF##w1 = *(const short8*)((WP) + 512);                         \
        BUF##w2 = *(const short8*)((WP) + 1024);                        \
        BUF##w3 = *(const short8*)((WP) + 1536);                        \
    }

#define PAIRSTEP(IP, WP, ARR, ROWOFF)                                   \
    {                                                                   \
        short8 a0 = Aa0, a1 = Aa1, a2 = Aa2, a3 = Aa3;                  \
        short8 w0 = Aw0, w1 = Aw1, w2 = Aw2, w3 = Aw3;                  \
        PREF(A, IP, WP, ARR, ROWOFF)                                    \
        ca = MFMA32(a0, w0, ca, 0, 0, 0);                               \
        ca = MFMA32(a1, w1, ca, 0, 0, 0);                               \
        ca = MFMA32(a2, w2, ca, 0, 0, 0);                               \
        ca = MFMA32(a3, w3, ca, 0, 0, 0);                               \
    }                                                                   \
    {                                                                   \
        short8 a0 = Ba0, a1 = Ba1, a2 = Ba2, a3 = Ba3;                  \
        short8 w0 = Bw0, w1 = Bw1, w2 = Bw2, w3 = Bw3;                  \
        PREF(B, (IP) + 8, (WP) + 2048, ARR, ROWOFF)                     \
        cb = MFMA32(a0, w0, cb, 0, 0, 0);                               \
        cb = MFMA32(a1, w1, cb, 0, 0, 0);                               \
        cb = MFMA32(a2, w2, cb, 0, 0, 0);                               \
        cb = MFMA32(a3, w3, cb, 0, 0, 0);                               \
    }                                                                   \
    IP += 16; WP += 4096; s += 16;

__global__ __launch_bounds__(NT, 3)
void bsffn_main(const float* __restrict__ x,
                const float* __restrict__ pb1, const float* __restrict__ pb2,
                const ushort_t* __restrict__ w1s, const ushort_t* __restrict__ w2s,
                const unsigned* __restrict__ idx1s, const unsigned* __restrict__ idx2s,
                const int* __restrict__ off1p, const int* __restrict__ off2p,
                float* __restrict__ out)
{
    __shared__ __align__(16) ushort_t xs[MR * XP];   // 49,792 B
    __shared__ __align__(16) ushort_t hs[MR * HP];   // 98,944 B (reused as f32 sacc)

    const int tid = threadIdx.x;
    const int wave = tid >> 6;                 // 0..11
    const int l = tid & 63;
    const int l31 = l & 31;
    const int lh = l >> 5;
    const int xrow = l31 * XP;
    const int hrow = l31 * HP;
    const int wlofs = lh * 256 + l31 * 8;
    const long rowBase = (long)blockIdx.x * MR;

    // ---- stage x tile -> bf16 LDS (linear) ----
    {
        const float* xr = x + rowBase * DIM;
        #pragma unroll
        for (int i = 0; i < 4; ++i) {
            int e = tid + i * NT;              // 32 rows x 96 col8-groups
            int row = e / 96, c8 = e % 96;
            const float4 v0 = *(const float4*)(xr + row * DIM + c8 * 8);
            const float4 v1 = *(const float4*)(xr + row * DIM + c8 * 8 + 4);
            uint4 wv;
            wv.x = (unsigned)f2bs(v0.x) | ((unsigned)f2bs(v0.y) << 16);
            wv.y = (unsigned)f2bs(v0.z) | ((unsigned)f2bs(v0.w) << 16);
            wv.z = (unsigned)f2bs(v1.x) | ((unsigned)f2bs(v1.y) << 16);
            wv.w = (unsigned)f2bs(v1.z) | ((unsigned)f2bs(v1.w) << 16);
            *(uint4*)&xs[row * XP + c8 * 8] = wv;
        }
    }

    f32x16 accA, accB;
    #pragma unroll
    for (int r = 0; r < 16; ++r) { accA[r] = 0.f; accB[r] = 0.f; }

    __syncthreads();

    for (int chunk = 0; chunk < 2; ++chunk) {
        // ---------- fc1: 4 contiguous groups, one linear stream ----------
        {
            const int Fbeg = chunk * 48 + wave * 4;
            int s = off1p[Fbeg];
            const unsigned* ip = idx1s + s;
            const ushort_t* wp = w1s + (long)s * 256 + wlofs;
            short8 Aa0, Aa1, Aa2, Aa3, Aw0, Aw1, Aw2, Aw3;
            short8 Ba0, Ba1, Ba2, Ba3, Bw0, Bw1, Bw2, Bw3;
            PREF(A, ip, wp, xs, xrow)
            PREF(B, ip + 8, wp + 2048, xs, xrow)
            ip += 16; wp += 4096;
            #pragma unroll 1
            for (int j = 0; j < 4; ++j) {
                const int F = Fbeg + j;
                const int gend = off1p[F + 1];
                f32x16 ca, cb;
                #pragma unroll
                for (int r = 0; r < 16; ++r) { ca[r] = 0.f; cb[r] = 0.f; }
                while (s < gend) { PAIRSTEP(ip, wp, xs, xrow) }
                const float bias = pb1[F * 32 + l31];
                const int hcol = (F - chunk * 48) * 32 + l31;
                #pragma unroll
                for (int r = 0; r < 16; ++r) {
                    int rs = (r & 3) + 8 * (r >> 2) + 4 * lh;   // D row (x-row)
                    hs[rs * HP + hcol] = f2bs(gelu_fast(ca[r] + cb[r] + bias));
                }
            }
        }
        __syncthreads();

        // ---------- fc2: 2 contiguous groups, persistent acc ----------
        {
            const int k0 = chunk * 24 + wave * 2;
            int s = off2p[k0];
            const unsigned* ip = idx2s + s;
            const ushort_t* wp = w2s + (long)s * 256 + wlofs;
            short8 Aa0, Aa1, Aa2, Aa3, Aw0, Aw1, Aw2, Aw3;
            short8 Ba0, Ba1, Ba2, Ba3, Bw0, Bw1, Bw2, Bw3;
            PREF(A, ip, wp, hs, hrow)
            PREF(B, ip + 8, wp + 2048, hs, hrow)
            ip += 16; wp += 4096;
            {   // group wave*2 -> accA
                const int gend = off2p[k0 + 1];
                f32x16 ca = accA, cb;
                #pragma unroll
                for (int r = 0; r < 16; ++r) cb[r] = 0.f;
                while (s < gend) { PAIRSTEP(ip, wp, hs, hrow) }
                #pragma unroll
                for (int r = 0; r < 16; ++r) accA[r] = ca[r] + cb[r];
            }
            {   // group wave*2+1 -> accB
                const int gend = off2p[k0 + 2];
                f32x16 ca = accB, cb;
                #pragma unroll
                for (int r = 0; r < 16; ++r) cb[r] = 0.f;
                while (s < gend) { PAIRSTEP(ip, wp, hs, hrow) }
                #pragma unroll
                for (int r = 0; r < 16; ++r) accB[r] = ca[r] + cb[r];
            }
        }
        __syncthreads();
    }

    // ---- epilogue: acc -> LDS (f32, pitch 773) -> coalesced float4 stores ----
    float* sacc = (float*)hs;                       // [32][773] = 98,944 B
    {
        const int d0 = (wave * 2) * 32 + l31;
        const int d1 = (wave * 2 + 1) * 32 + l31;
        #pragma unroll
        for (int r = 0; r < 16; ++r) {
            int rs = (r & 3) + 8 * (r >> 2) + 4 * lh;
            sacc[rs * SACCP + d0] = accA[r];
            sacc[rs * SACCP + d1] = accB[r];
        }
    }
    __syncthreads();
    {
        const float4* pb24 = (const float4*)pb2;
        #pragma unroll
        for (int i = 0; i < 8; ++i) {
            int e = tid + i * NT;                   // 32 rows x 192 float4
            int row = e / 192, c4 = e % 192;
            float4 v = *(const float4*)&sacc[row * SACCP + c4 * 4];
            float4 b = pb24[c4];
            v.x += b.x; v.y += b.y; v.z += b.z; v.w += b.w;
            *(float4*)&out[(rowBase + row) * DIM + c4 * 4] = v;
        }
    }
}

extern "C" void kernel_launch(void* const* d_in, const int* in_sizes, int n_in,
                              void* d_out, int out_size, void* d_ws, size_t ws_size,
                              hipStream_t stream) {
    const float* x = (const float*)d_in[0];
    const float* W1 = (const float*)d_in[1];
    const float* b1 = (const float*)d_in[2];
    const float* W2 = (const float*)d_in[3];
    const float* b2 = (const float*)d_in[4];
    const int* mask1 = (const int*)d_in[5];
    const int* mask2 = (const int*)d_in[6];
    float* out = (float*)d_out;

    // ws layout (~9.6 MiB)
    ushort_t* w1s = (ushort_t*)d_ws;
    ushort_t* w2s = w1s + W1S_TOT;
    unsigned* idx1s = (unsigned*)(w2s + W2S_TOT);
    unsigned* idx2s = idx1s + S1CAP;
    int* cnt1 = (int*)(idx2s + S2CAP);
    int* cnt2 = cnt1 + NF32;
    int* off1p = cnt2 + 2 * NG32;
    int* off2p = off1p + (NF32 + 1);
    int* base1 = off2p + (2 * NG32 + 1);
    int* base2 = base1 + NF32;

    prep_count<<<NF32 + NG32, 64, 0, stream>>>(mask1, mask2, cnt1, cnt2);
    prep_scan<<<1, 128, 0, stream>>>(cnt1, cnt2, off1p, off2p, base1, base2,
                                     idx1s, idx2s);
    prep_gather<<<NF32 + 2 * NG32, 256, 0, stream>>>(
        W1, W2, mask1, mask2, base1, base2, cnt1, cnt2,
        (__hip_bfloat16*)w1s, (__hip_bfloat16*)w2s, idx1s, idx2s);

    const int rows = in_sizes[0] / DIM;        // 36928
    const int nblk = rows / MR;                // 1154
    bsffn_main<<<nblk, NT, 0, stream>>>(
        x, b1, b2, w1s, w2s, idx1s, idx2s, off1p, off2p, out);
}

// Round 15
// 361.045 us; speedup vs baseline: 1.8535x; 1.8535x over previous
//
#include <hip/hip_runtime.h>
#include <hip/hip_bf16.h>

// Block-sparse FFN via compacted-weight MFMA, v15 (restore: aligned pitches).
//   out = gelu(x @ (W1*M1)^T + b1) @ (W2*M2)^T + b2
// = v14 (direct __shared__ indexing -> ds_read_b128, u32 element-offset idx,
//   no swizzle, identity assignment) with v10's 16B-ALIGNED pitches restored:
//   XP=776 (row 1552B = 16*97), HP=1544 (3088B = 16*193). v14's odd-dword
//   pitches made every A-gather an UNALIGNED b128 (row stride 1556B % 16 = 4)
//   -> LDS slow path, 689us. Alignment > bank micro-optimization.

typedef __attribute__((ext_vector_type(8))) short short8;
typedef __attribute__((ext_vector_type(16))) float f32x16;
typedef unsigned long long u64;
typedef unsigned short ushort_t;

#define DIM 768
#define FF 3072
#define NF32 96             // fc1 32-col groups
#define NG32 24             // fc2 32-col groups
#define NDB 96
#define NFB 384
#define MR 32
#define NT 768
#define XP 776              // xs pitch (bf16) -> row 1552 B, 16B-aligned
#define HP 1544             // hs pitch (bf16) -> row 3088 B, 16B-aligned
#define SACCP 772           // sacc pitch (f32): 32*772*4 = 98,816 B = sizeof(hs)

#define S1CAP (NF32 * 96 + 32)        // slots + prefetch margin
#define S2CAP (NG32 * 2 * 192 + 32)
#define W1S_TOT (S1CAP * 256)         // bf16 elems
#define W2S_TOT (S2CAP * 256)

#define MFMA32 __builtin_amdgcn_mfma_f32_32x32x16_bf16

__device__ __forceinline__ float gelu_fast(float v) {
    float t2 = v * fmaf(v * v, -0.10295667f, -2.30235629f);
    return v / (1.0f + exp2f(t2));
}
__device__ __forceinline__ ushort_t f2bs(float f) {
    union { __hip_bfloat16 h; ushort_t u; } cv;
    cv.h = __float2bfloat16(f);
    return cv.u;
}

// ---------------- prep 1: padded per-group counts ----------------
__global__ __launch_bounds__(64)
void prep_count(const int* __restrict__ mask1, const int* __restrict__ mask2,
                int* __restrict__ cnt1, int* __restrict__ cnt2)
{
    const int l = threadIdx.x;
    const int g = blockIdx.x;
    if (g < NF32) {
        const int* r0 = mask1 + (4 * g) * NDB;
        bool ua = (r0[l] | r0[NDB + l] | r0[2 * NDB + l] | r0[3 * NDB + l]) != 0;
        u64 ba = __ballot(ua);
        bool ub = (l < 32) &&
            ((r0[64 + l] | r0[NDB + 64 + l] | r0[2 * NDB + 64 + l] | r0[3 * NDB + 64 + l]) != 0);
        u64 bb = __ballot(ub);
        if (l == 0) cnt1[g] = ((__popcll(ba) + __popcll(bb)) + 15) & ~15;
    } else {
        const int G = g - NF32;
        const int* r0 = mask2 + (4 * G) * NFB;
        int c0 = 0, c1 = 0;
        #pragma unroll
        for (int p = 0; p < 6; ++p) {
            int fb = p * 64 + l;
            u64 b = __ballot((r0[fb] | r0[NFB + fb] | r0[2 * NFB + fb] | r0[3 * NFB + fb]) != 0);
            if (p < 3) c0 += __popcll(b); else c1 += __popcll(b);
        }
        if (l == 0) {
            cnt2[0 * NG32 + G] = (c0 + 15) & ~15;
            cnt2[1 * NG32 + G] = (c1 + 15) & ~15;
        }
    }
}

// ---------------- prep 2: trivial parallel prefix + tails ----------------
__global__ __launch_bounds__(128)
void prep_scan(const int* __restrict__ cnt1, const int* __restrict__ cnt2,
               int* __restrict__ off1p, int* __restrict__ off2p,
               int* __restrict__ base1, int* __restrict__ base2,
               unsigned* __restrict__ idx1s, unsigned* __restrict__ idx2s)
{
    __shared__ int s1[97], s2[49];
    const int tid = threadIdx.x;
    if (tid < 96) s1[tid + 1] = cnt1[tid];
    if (tid < 48) s2[tid + 1] = cnt2[tid];
    __syncthreads();
    if (tid == 0) { s1[0] = 0; for (int i = 0; i < 96; ++i) s1[i + 1] += s1[i]; }
    if (tid == 1) { s2[0] = 0; for (int i = 0; i < 48; ++i) s2[i + 1] += s2[i]; }
    __syncthreads();
    if (tid < 97) off1p[tid] = s1[tid];
    if (tid < 96) base1[tid] = s1[tid];
    if (tid < 49) off2p[tid] = s2[tid];
    if (tid < 48) base2[tid] = s2[tid];
    if (tid >= 64 && tid < 96) idx1s[s1[96] + (tid - 64)] = 0;    // safe overrun
    if (tid >= 96 && tid < 128) idx2s[s2[48] + (tid - 96)] = 0;
}

// ---------------- prep 3: gather weights + u32 element-offset indices ----------------
__global__ __launch_bounds__(256)
void prep_gather(const float* __restrict__ W1, const float* __restrict__ W2,
                 const int* __restrict__ mask1, const int* __restrict__ mask2,
                 const int* __restrict__ base1, const int* __restrict__ base2,
                 const int* __restrict__ cnt1, const int* __restrict__ cnt2,
                 __hip_bfloat16* __restrict__ w1s, __hip_bfloat16* __restrict__ w2s,
                 unsigned* __restrict__ idx1s, unsigned* __restrict__ idx2s)
{
    __shared__ ushort_t sidx[192];
    __shared__ int sc[1];
    const int tid = threadIdx.x;
    const int l = tid & 63;
    const int g = blockIdx.x;

    if (g < NF32) {                       // ---- fc1 group F ----
        const int F = g;
        const int* r0 = mask1 + (4 * F) * NDB;
        if (tid < 64) {
            bool ua = (r0[l] | r0[NDB + l] | r0[2 * NDB + l] | r0[3 * NDB + l]) != 0;
            u64 ba = __ballot(ua);
            bool ub = (l < 32) &&
                ((r0[64 + l] | r0[NDB + 64 + l] | r0[2 * NDB + 64 + l] | r0[3 * NDB + 64 + l]) != 0);
            u64 bb = __ballot(ub);
            int ca = __popcll(ba);
            if (ua) sidx[__popcll(ba & ((1ull << l) - 1ull))] = (ushort_t)l;
            if (ub) sidx[ca + __popcll(bb & ((1ull << l) - 1ull))] = (ushort_t)(64 + l);
            int cnt = ca + __popcll(bb);
            if (l == 0) {
                sc[0] = cnt;
                int cntp = (cnt + 15) & ~15;
                for (int i = cnt; i < cntp && i < 192; ++i) sidx[i] = 0;
            }
        }
        __syncthreads();
        const int cnt = sc[0];
        const int base = base1[F];
        const int cntp = cnt1[F];
        if (tid < cntp) idx1s[base + tid] = (unsigned)sidx[tid] * 8u;  // elem offset
        for (int e = tid; e < cntp * 256; e += 256) {
            int slot = e >> 8, c = (e >> 3) & 31, j = e & 7;
            int db = sidx[slot];
            float w = 0.f;
            if (slot < cnt && mask1[(4 * F + (c >> 3)) * NDB + db])
                w = W1[(long)(F * 32 + c) * DIM + db * 8 + j];
            w1s[(long)(base + slot) * 256 + c * 8 + j] = __float2bfloat16(w);
        }
    } else {                              // ---- fc2 (chunk, G) ----
        const int gi = g - NF32;
        const int c = gi / NG32;
        const int G = gi % NG32;
        const int* r0 = mask2 + (4 * G) * NFB;
        if (tid < 64) {
            u64 b[3]; int pc[3];
            #pragma unroll
            for (int p = 0; p < 3; ++p) {
                int fb = c * 192 + p * 64 + l;
                b[p] = __ballot((r0[fb] | r0[NFB + fb] | r0[2 * NFB + fb] | r0[3 * NFB + fb]) != 0);
                pc[p] = __popcll(b[p]);
            }
            int basea = 0;
            #pragma unroll
            for (int p = 0; p < 3; ++p) {
                if ((b[p] >> l) & 1ull)
                    sidx[basea + __popcll(b[p] & ((1ull << l) - 1ull))] = (ushort_t)(p * 64 + l);
                basea += pc[p];
            }
            if (l == 0) {
                int cnt = basea;
                sc[0] = cnt;
                int cntp = (cnt + 15) & ~15;
                for (int i = cnt; i < cntp && i < 192; ++i) sidx[i] = 0;
            }
        }
        __syncthreads();
        const int cnt = sc[0];
        const int base = base2[c * NG32 + G];
        const int cntp = cnt2[c * NG32 + G];
        if (tid < cntp) idx2s[base + tid] = (unsigned)sidx[tid] * 8u;  // elem offset
        for (int e = tid; e < cntp * 256; e += 256) {
            int slot = e >> 8, cc = (e >> 3) & 31, j = e & 7;
            int lfb = sidx[slot];
            int fb = c * 192 + lfb;
            float w = 0.f;
            if (slot < cnt && mask2[(4 * G + (cc >> 3)) * NFB + fb])
                w = W2[(long)(G * 32 + cc) * FF + fb * 8 + j];
            w2s[(long)(base + slot) * 256 + cc * 8 + j] = __float2bfloat16(w);
        }
    }
}

// ---------------- main fused kernel ----------------
// PREF: m* are u32 ELEMENT offsets; gathers index the __shared__ array directly
// (compiler proves LDS addrspace -> aligned ds_read_b128).
#define PREF(BUF, IP, WP, ARR, ROWOFF)                                  \
    {                                                                   \
        uint4 qa = *(const uint4*)(IP);                                 \
        uint4 qb = *(const uint4*)((IP) + 4);                           \
        int m0 = lh ? (int)qa.y : (int)qa.x;                            \
        int m1 = lh ? (int)qa.w : (int)qa.z;                            \
        int m2 = lh ? (int)qb.y : (int)qb.x;                            \
        int m3 = lh ? (int)qb.w : (int)qb.z;                            \
        BUF##a0 = *(const short8*)&ARR[(ROWOFF) + m0];                  \
        BUF##a1 = *(const short8*)&ARR[(ROWOFF) + m1];                  \
        BUF##a2 = *(const short8*)&ARR[(ROWOFF) + m2];                  \
        BUF##a3 = *(const short8*)&ARR[(ROWOFF) + m3];                  \
        BUF##w0 = *(const short8*)(WP);                                 \
        BUF##w1 = *(const short8*)((WP) + 512);                         \
        BUF##w2 = *(const short8*)((WP) + 1024);                        \
        BUF##w3 = *(const short8*)((WP) + 1536);                        \
    }

#define PAIRSTEP(IP, WP, ARR, ROWOFF)                                   \
    {                                                                   \
        short8 a0 = Aa0, a1 = Aa1, a2 = Aa2, a3 = Aa3;                  \
        short8 w0 = Aw0, w1 = Aw1, w2 = Aw2, w3 = Aw3;                  \
        PREF(A, IP, WP, ARR, ROWOFF)                                    \
        ca = MFMA32(a0, w0, ca, 0, 0, 0);                               \
        ca = MFMA32(a1, w1, ca, 0, 0, 0);                               \
        ca = MFMA32(a2, w2, ca, 0, 0, 0);                               \
        ca = MFMA32(a3, w3, ca, 0, 0, 0);                               \
    }                                                                   \
    {                                                                   \
        short8 a0 = Ba0, a1 = Ba1, a2 = Ba2, a3 = Ba3;                  \
        short8 w0 = Bw0, w1 = Bw1, w2 = Bw2, w3 = Bw3;                  \
        PREF(B, (IP) + 8, (WP) + 2048, ARR, ROWOFF)                     \
        cb = MFMA32(a0, w0, cb, 0, 0, 0);                               \
        cb = MFMA32(a1, w1, cb, 0, 0, 0);                               \
        cb = MFMA32(a2, w2, cb, 0, 0, 0);                               \
        cb = MFMA32(a3, w3, cb, 0, 0, 0);                               \
    }                                                                   \
    IP += 16; WP += 4096; s += 16;

__global__ __launch_bounds__(NT, 3)
void bsffn_main(const float* __restrict__ x,
                const float* __restrict__ pb1, const float* __restrict__ pb2,
                const ushort_t* __restrict__ w1s, const ushort_t* __restrict__ w2s,
                const unsigned* __restrict__ idx1s, const unsigned* __restrict__ idx2s,
                const int* __restrict__ off1p, const int* __restrict__ off2p,
                float* __restrict__ out)
{
    __shared__ __align__(16) ushort_t xs[MR * XP];   // 49,664 B
    __shared__ __align__(16) ushort_t hs[MR * HP];   // 98,816 B (reused as f32 sacc)

    const int tid = threadIdx.x;
    const int wave = tid >> 6;                 // 0..11
    const int l = tid & 63;
    const int l31 = l & 31;
    const int lh = l >> 5;
    const int xrow = l31 * XP;
    const int hrow = l31 * HP;
    const int wlofs = lh * 256 + l31 * 8;
    const long rowBase = (long)blockIdx.x * MR;

    // ---- stage x tile -> bf16 LDS (linear) ----
    {
        const float* xr = x + rowBase * DIM;
        #pragma unroll
        for (int i = 0; i < 4; ++i) {
            int e = tid + i * NT;              // 32 rows x 96 col8-groups
            int row = e / 96, c8 = e % 96;
            const float4 v0 = *(const float4*)(xr + row * DIM + c8 * 8);
            const float4 v1 = *(const float4*)(xr + row * DIM + c8 * 8 + 4);
            uint4 wv;
            wv.x = (unsigned)f2bs(v0.x) | ((unsigned)f2bs(v0.y) << 16);
            wv.y = (unsigned)f2bs(v0.z) | ((unsigned)f2bs(v0.w) << 16);
            wv.z = (unsigned)f2bs(v1.x) | ((unsigned)f2bs(v1.y) << 16);
            wv.w = (unsigned)f2bs(v1.z) | ((unsigned)f2bs(v1.w) << 16);
            *(uint4*)&xs[row * XP + c8 * 8] = wv;
        }
    }

    f32x16 accA, accB;
    #pragma unroll
    for (int r = 0; r < 16; ++r) { accA[r] = 0.f; accB[r] = 0.f; }

    __syncthreads();

    for (int chunk = 0; chunk < 2; ++chunk) {
        // ---------- fc1: 4 contiguous groups, one linear stream ----------
        {
            const int Fbeg = chunk * 48 + wave * 4;
            int s = off1p[Fbeg];
            const unsigned* ip = idx1s + s;
            const ushort_t* wp = w1s + (long)s * 256 + wlofs;
            short8 Aa0, Aa1, Aa2, Aa3, Aw0, Aw1, Aw2, Aw3;
            short8 Ba0, Ba1, Ba2, Ba3, Bw0, Bw1, Bw2, Bw3;
            PREF(A, ip, wp, xs, xrow)
            PREF(B, ip + 8, wp + 2048, xs, xrow)
            ip += 16; wp += 4096;
            #pragma unroll 1
            for (int j = 0; j < 4; ++j) {
                const int F = Fbeg + j;
                const int gend = off1p[F + 1];
                f32x16 ca, cb;
                #pragma unroll
                for (int r = 0; r < 16; ++r) { ca[r] = 0.f; cb[r] = 0.f; }
                while (s < gend) { PAIRSTEP(ip, wp, xs, xrow) }
                const float bias = pb1[F * 32 + l31];
                const int hcol = (F - chunk * 48) * 32 + l31;
                #pragma unroll
                for (int r = 0; r < 16; ++r) {
                    int rs = (r & 3) + 8 * (r >> 2) + 4 * lh;   // D row (x-row)
                    hs[rs * HP + hcol] = f2bs(gelu_fast(ca[r] + cb[r] + bias));
                }
            }
        }
        __syncthreads();

        // ---------- fc2: 2 contiguous groups, persistent acc ----------
        {
            const int k0 = chunk * 24 + wave * 2;
            int s = off2p[k0];
            const unsigned* ip = idx2s + s;
            const ushort_t* wp = w2s + (long)s * 256 + wlofs;
            short8 Aa0, Aa1, Aa2, Aa3, Aw0, Aw1, Aw2, Aw3;
            short8 Ba0, Ba1, Ba2, Ba3, Bw0, Bw1, Bw2, Bw3;
            PREF(A, ip, wp, hs, hrow)
            PREF(B, ip + 8, wp + 2048, hs, hrow)
            ip += 16; wp += 4096;
            {   // group wave*2 -> accA
                const int gend = off2p[k0 + 1];
                f32x16 ca = accA, cb;
                #pragma unroll
                for (int r = 0; r < 16; ++r) cb[r] = 0.f;
                while (s < gend) { PAIRSTEP(ip, wp, hs, hrow) }
                #pragma unroll
                for (int r = 0; r < 16; ++r) accA[r] = ca[r] + cb[r];
            }
            {   // group wave*2+1 -> accB
                const int gend = off2p[k0 + 2];
                f32x16 ca = accB, cb;
                #pragma unroll
                for (int r = 0; r < 16; ++r) cb[r] = 0.f;
                while (s < gend) { PAIRSTEP(ip, wp, hs, hrow) }
                #pragma unroll
                for (int r = 0; r < 16; ++r) accB[r] = ca[r] + cb[r];
            }
        }
        __syncthreads();
    }

    // ---- epilogue: acc -> LDS (f32, pitch 772) -> coalesced float4 stores ----
    float* sacc = (float*)hs;                       // [32][772] = 98,816 B
    {
        const int d0 = (wave * 2) * 32 + l31;
        const int d1 = (wave * 2 + 1) * 32 + l31;
        #pragma unroll
        for (int r = 0; r < 16; ++r) {
            int rs = (r & 3) + 8 * (r >> 2) + 4 * lh;
            sacc[rs * SACCP + d0] = accA[r];
            sacc[rs * SACCP + d1] = accB[r];
        }
    }
    __syncthreads();
    {
        const float4* pb24 = (const float4*)pb2;
        #pragma unroll
        for (int i = 0; i < 8; ++i) {
            int e = tid + i * NT;                   // 32 rows x 192 float4
            int row = e / 192, c4 = e % 192;
            float4 v = *(const float4*)&sacc[row * SACCP + c4 * 4];
            float4 b = pb24[c4];
            v.x += b.x; v.y += b.y; v.z += b.z; v.w += b.w;
            *(float4*)&out[(rowBase + row) * DIM + c4 * 4] = v;
        }
    }
}

extern "C" void kernel_launch(void* const* d_in, const int* in_sizes, int n_in,
                              void* d_out, int out_size, void* d_ws, size_t ws_size,
                              hipStream_t stream) {
    const float* x = (const float*)d_in[0];
    const float* W1 = (const float*)d_in[1];
    const float* b1 = (const float*)d_in[2];
    const float* W2 = (const float*)d_in[3];
    const float* b2 = (const float*)d_in[4];
    const int* mask1 = (const int*)d_in[5];
    const int* mask2 = (const int*)d_in[6];
    float* out = (float*)d_out;

    // ws layout (~9.6 MiB)
    ushort_t* w1s = (ushort_t*)d_ws;
    ushort_t* w2s = w1s + W1S_TOT;
    unsigned* idx1s = (unsigned*)(w2s + W2S_TOT);
    unsigned* idx2s = idx1s + S1CAP;
    int* cnt1 = (int*)(idx2s + S2CAP);
    int* cnt2 = cnt1 + NF32;
    int* off1p = cnt2 + 2 * NG32;
    int* off2p = off1p + (NF32 + 1);
    int* base1 = off2p + (2 * NG32 + 1);
    int* base2 = base1 + NF32;

    prep_count<<<NF32 + NG32, 64, 0, stream>>>(mask1, mask2, cnt1, cnt2);
    prep_scan<<<1, 128, 0, stream>>>(cnt1, cnt2, off1p, off2p, base1, base2,
                                     idx1s, idx2s);
    prep_gather<<<NF32 + 2 * NG32, 256, 0, stream>>>(
        W1, W2, mask1, mask2, base1, base2, cnt1, cnt2,
        (__hip_bfloat16*)w1s, (__hip_bfloat16*)w2s, idx1s, idx2s);

    const int rows = in_sizes[0] / DIM;        // 36928
    const int nblk = rows / MR;                // 1154
    bsffn_main<<<nblk, NT, 0, stream>>>(
        x, b1, b2, w1s, w2s, idx1s, idx2s, off1p, off2p, out);
}